// Round 3
// baseline (1743.851 us; speedup 1.0000x reference)
//
#include <hip/hip_runtime.h>
#include <cstdint>
#include <cstddef>

// BiLSTM-CRF forward, MI355X fp32 implementation.
// Pipeline: prep -> proj1(emb gather GEMM) -> lstm1(256 fused chains) -> proj2
//           -> lstm2(32 fused chains) -> emission -> viterbi(+backtrace).
//
// R6 (this round): staggered same-direction chain FUSION.
//   Counters showed lstm2 at 597us with active-CU VALUBusy ~32%: each step is
//   512 cyc of matvec issue + ~1300 cyc of serial latency (2 barriers, psum
//   and h LDS round trips, transcendental chain on 2 of 8 waves).
//   VGPR_Count=120 (+~128 AGPR weights) => 8 waves/CU, register file holds
//   exactly ONE chain's weights -> cannot co-schedule two weight sets.
//   Fix: fuse TWO chains that SHARE Whh (same direction) into one block:
//     even interval: [reduce B(it-1)  ||  matvec A(it)]  BAR
//     odd  interval: [reduce A(it)    ||  matvec B(it)]  BAR
//   One barrier per interval (was 2/step), and the reduce latency of one
//   chain hides under the other chain's matvec issue. Per-step global access
//   needs no KS-grouping: raw barriers never drain vmcnt, hn stores are
//   fire-and-forget, xv is a 2-deep register pipeline loaded 4 intervals
//   (~2500 cyc) ahead of use.
//   lstm1: (b, seg 2k/2k+1, dir) pairs -> 256 blocks, one dispatch round.
//   lstm2: same-dir batch pairs, complement-paired by sorted new_len
//   (block cost ~ 450*min + 1050*max cyc -> pair longest with shortest).

#define B_    32
#define NSEG_ 8
#define S_    128
#define T_    1024
#define E_    256
#define HD_   128
#define G_    512   // 4*HD
#define K_    16

#define PIN4(v) asm volatile("" : "+v"((v).x), "+v"((v).y), "+v"((v).z), "+v"((v).w))

// Barrier that does NOT drain vmcnt: LDS writes made visible (lgkmcnt(0)),
// rendezvous, then a hard scheduling fence so following LDS reads can't
// hoist above the barrier (rule #18).
#define BAR_LDS() do {                                        \
    asm volatile("s_waitcnt lgkmcnt(0)" ::: "memory");        \
    __builtin_amdgcn_s_barrier();                             \
    __builtin_amdgcn_sched_barrier(0);                        \
} while (0)

// ---------------- prep: seg offsets, fused+permuted bias, permuted Wih^T, lstm2 pairs ----------------
// Gate-interleaved column n in [0,1024): dir=n>>9, j=(n>>2)&127, g=n&3
// maps to LSTM gate row (g*128+j) of direction dir.
__global__ void prep_kernel(const int* __restrict__ lengths,
                            int* __restrict__ seg_off, int* __restrict__ new_len,
                            int* __restrict__ pairs,
                            const float* __restrict__ bih_f, const float* __restrict__ bhh_f,
                            const float* __restrict__ bih_b, const float* __restrict__ bhh_b,
                            float* __restrict__ bias1,
                            const float* __restrict__ Wih_f, const float* __restrict__ Wih_b,
                            float* __restrict__ WT1)
{
    __shared__ int s_len[B_];
    __shared__ int s_sorted[B_];
    int gtid = blockIdx.x * blockDim.x + threadIdx.x;
    if (gtid < B_) {
        int acc = 0;
        for (int s = 0; s < NSEG_; s++) { seg_off[gtid*NSEG_ + s] = acc; acc += lengths[gtid*NSEG_ + s]; }
        new_len[gtid] = acc;
    }
    if (gtid < 1024) {
        int n = gtid, dir = n >> 9, j = (n >> 2) & 127, g = n & 3;
        int row = g*128 + j;
        bias1[n] = dir ? (bih_b[row] + bhh_b[row]) : (bih_f[row] + bhh_f[row]);
    }
    // lstm2 pairing: block 0 computes sums, rank-sorts 32, complement-pairs.
    if (blockIdx.x == 0) {
        int t = threadIdx.x;
        if (t < B_) {
            int acc = 0;
            for (int s = 0; s < NSEG_; s++) acc += lengths[t*NSEG_ + s];
            s_len[t] = acc;
        }
        __syncthreads();
        if (t < B_) {
            int my = s_len[t], rank = 0;
            for (int u = 0; u < B_; u++) {
                int lu = s_len[u];
                if (lu < my || (lu == my && u < t)) rank++;
            }
            s_sorted[rank] = t;
        }
        __syncthreads();
        if (t < B_/2) { pairs[2*t] = s_sorted[t]; pairs[2*t+1] = s_sorted[B_-1-t]; }
    }
    // WT1[k][n] (256 x 1024): column n holds Wih row (g*128+j) of dir.
    for (int e = gtid; e < 256*1024; e += gridDim.x * blockDim.x) {
        int k = e >> 10, n = e & 1023;
        int dir = n >> 9, j = (n >> 2) & 127, g = n & 3;
        int row = g*128 + j;
        WT1[e] = dir ? Wih_b[row*E_ + k] : Wih_f[row*E_ + k];
    }
}

// ---------------- projection GEMM: xproj[b][p][n] = A[p][:] . WT1[:][n] + bias1[n] ----------------
template <int MODE>
__global__ void __launch_bounds__(256, 4)
proj_kernel(const int* __restrict__ texts, const float* __restrict__ emb,
            const float* __restrict__ WT1, const float* __restrict__ bias1,
            const float* __restrict__ lstm_packed, float* __restrict__ xproj,
            const int* __restrict__ seg_off, const int* __restrict__ new_len)
{
    int b  = blockIdx.z;
    int nl = new_len[b];
    int p0 = blockIdx.x * 32;
    if (p0 >= nl) return;
    int j0 = blockIdx.y * 256;

    __shared__ __align__(16) float As[32][256];
    __shared__ const float* rowp[32];
    int tid = threadIdx.x;
    if (tid < 32) {
        int p = p0 + tid;
        const float* r = emb;  // dummy row for invalid p
        if (p < nl) {
            if (MODE == 0) {
                int sg = 0;
                #pragma unroll
                for (int q = 1; q < NSEG_; q++) if (seg_off[b*NSEG_ + q] <= p) sg = q;
                int t   = p - seg_off[b*NSEG_ + sg];
                int tok = texts[(b*NSEG_ + sg)*S_ + t];
                r = emb + (size_t)tok * E_;
            } else {
                r = lstm_packed + ((size_t)b*T_ + p) * 256;
            }
        }
        rowp[tid] = r;
    }
    __syncthreads();
    #pragma unroll 4
    for (int i = 0; i < 32; i++) As[i][tid] = rowp[i][tid];
    __syncthreads();

    int pg = tid >> 6;
    int jg = tid & 63;
    int j  = j0 + jg*4;
    float acc[8][4];
    #pragma unroll
    for (int i = 0; i < 8; i++) { acc[i][0]=0.f; acc[i][1]=0.f; acc[i][2]=0.f; acc[i][3]=0.f; }

    const float* wbase = WT1 + j;
    for (int k = 0; k < 256; k += 4) {
        float4 w0 = *(const float4*)(wbase + (size_t)(k+0)*1024);
        float4 w1 = *(const float4*)(wbase + (size_t)(k+1)*1024);
        float4 w2 = *(const float4*)(wbase + (size_t)(k+2)*1024);
        float4 w3 = *(const float4*)(wbase + (size_t)(k+3)*1024);
        #pragma unroll
        for (int i = 0; i < 8; i++) {
            float4 a = *(const float4*)&As[pg*8 + i][k];
            acc[i][0] = fmaf(a.w, w3.x, fmaf(a.z, w2.x, fmaf(a.y, w1.x, fmaf(a.x, w0.x, acc[i][0]))));
            acc[i][1] = fmaf(a.w, w3.y, fmaf(a.z, w2.y, fmaf(a.y, w1.y, fmaf(a.x, w0.y, acc[i][1]))));
            acc[i][2] = fmaf(a.w, w3.z, fmaf(a.z, w2.z, fmaf(a.y, w1.z, fmaf(a.x, w0.z, acc[i][2]))));
            acc[i][3] = fmaf(a.w, w3.w, fmaf(a.z, w2.w, fmaf(a.y, w1.w, fmaf(a.x, w0.w, acc[i][3]))));
        }
    }
    float4 bs = *(const float4*)(bias1 + j);
    #pragma unroll
    for (int i = 0; i < 8; i++) {
        int p = p0 + pg*8 + i;
        if (p < nl) {
            float4 r;
            r.x = acc[i][0] + bs.x; r.y = acc[i][1] + bs.y;
            r.z = acc[i][2] + bs.z; r.w = acc[i][3] + bs.w;
            *(float4*)(xproj + (((size_t)b*T_ + p) << 10) + j) = r;
        }
    }
}

// ---------------- fused staggered LSTM pair ----------------
__device__ __forceinline__ float sig_f(float x) { return 1.0f / (1.0f + __expf(-x)); }
__device__ __forceinline__ float tanh_f(float x) {
    float xc = fminf(fmaxf(x, -15.0f), 15.0f);
    float e  = __expf(-2.0f * xc);
    return (1.0f - e) / (1.0f + e);
}

__device__ __forceinline__ void matvec_step(const float4 (&w)[4][8],
                                            const float* __restrict__ h_sh,
                                            float4* __restrict__ psum,
                                            int j, int q)
{
    const float4* hv = (const float4*)h_sh + q * 8;
    float4 a0 = make_float4(0.f,0.f,0.f,0.f);
    float4 a1 = a0, a2 = a0, a3 = a0;
    #pragma unroll
    for (int i = 0; i < 8; i++) {
        float4 h4 = hv[i];
        a0.x = fmaf(h4.x, w[0][i].x, a0.x); a0.y = fmaf(h4.y, w[0][i].y, a0.y);
        a0.z = fmaf(h4.z, w[0][i].z, a0.z); a0.w = fmaf(h4.w, w[0][i].w, a0.w);
        a1.x = fmaf(h4.x, w[1][i].x, a1.x); a1.y = fmaf(h4.y, w[1][i].y, a1.y);
        a1.z = fmaf(h4.z, w[1][i].z, a1.z); a1.w = fmaf(h4.w, w[1][i].w, a1.w);
        a2.x = fmaf(h4.x, w[2][i].x, a2.x); a2.y = fmaf(h4.y, w[2][i].y, a2.y);
        a2.z = fmaf(h4.z, w[2][i].z, a2.z); a2.w = fmaf(h4.w, w[2][i].w, a2.w);
        a3.x = fmaf(h4.x, w[3][i].x, a3.x); a3.y = fmaf(h4.y, w[3][i].y, a3.y);
        a3.z = fmaf(h4.z, w[3][i].z, a3.z); a3.w = fmaf(h4.w, w[3][i].w, a3.w);
    }
    psum[q*128 + j] = make_float4((a0.x+a0.y)+(a0.z+a0.w),
                                  (a1.x+a1.y)+(a1.z+a1.w),
                                  (a2.x+a2.y)+(a2.z+a2.w),
                                  (a3.x+a3.y)+(a3.z+a3.w));
}

__device__ __forceinline__ float reduce_step(const float4* __restrict__ ps,
                                             float4 xv, float& c_reg,
                                             float* __restrict__ h_sh, int j)
{
    float4 p0 = ps[j], p1 = ps[128 + j], p2 = ps[256 + j], p3 = ps[384 + j];
    float gi = xv.x + ((p0.x + p1.x) + (p2.x + p3.x));
    float gf = xv.y + ((p0.y + p1.y) + (p2.y + p3.y));
    float gg = xv.z + ((p0.z + p1.z) + (p2.z + p3.z));
    float go = xv.w + ((p0.w + p1.w) + (p2.w + p3.w));
    float cn = sig_f(gf) * c_reg + sig_f(gi) * tanh_f(gg);
    c_reg = cn;
    float hn = sig_f(go) * tanh_f(cn);
    h_sh[j] = hn;
    return hn;
}

// Two chains A, B of the SAME direction (shared Whh) in one 512-thread block.
// Schedule (1 barrier per interval):
//   even(it): [reduce B(it-1) || matvec A(it)]  BAR
//   odd (it): [reduce A(it)   || matvec B(it)]  BAR
__device__ __forceinline__ void lstm_fused(
    const float* __restrict__ Whh,
    const float* __restrict__ xpA, const float* __restrict__ xpB,
    float* __restrict__ outA, float* __restrict__ outB,
    int pbA, int lenA, int pbB, int lenB, int dir,
    const float* __restrict__ h0A, const float* __restrict__ c0A,
    const float* __restrict__ h0B, const float* __restrict__ c0B,
    float* __restrict__ hTA, float* __restrict__ cTA,
    float* __restrict__ hTB, float* __restrict__ cTB)
{
    __shared__ __align__(16) float  h_A[HD_], h_B[HD_];
    __shared__ __align__(16) float4 psA[4*HD_], psB[4*HD_];
    int t = threadIdx.x;          // 0..511
    int j = t & 127, q = t >> 7;  // per-wave q uniform -> h reads broadcast

    // Shared weights: gate rows j+128g, k in [32q,32q+32). Pinned (128 regs).
    float4 w[4][8];
    #pragma unroll
    for (int g = 0; g < 4; g++) {
        const float4* wr = (const float4*)(Whh + (size_t)(j + 128*g) * HD_ + 32*q);
        #pragma unroll
        for (int i = 0; i < 8; i++) { w[g][i] = wr[i]; PIN4(w[g][i]); }
    }

    float cA = 0.0f, cB = 0.0f;
    if (t < HD_) {
        h_A[t] = h0A ? h0A[t] : 0.0f;  cA = c0A ? c0A[t] : 0.0f;
        h_B[t] = h0B ? h0B[t] : 0.0f;  cB = c0B ? c0B[t] : 0.0f;
    }

    const float4* xcA = (const float4*)(xpA + (size_t)dir * G_) + j;
    const float4* xcB = (const float4*)(xpB + (size_t)dir * G_) + j;
    const int rev = dir;
    const int oco = dir * HD_ + j;

    auto pA = [&](int s) { return pbA + (rev ? (lenA - 1 - s) : s); };
    auto pB = [&](int s) { return pbB + (rev ? (lenB - 1 - s) : s); };

    // 2-deep xv register pipeline per chain (loads issued 4 intervals ahead).
    float4 zero4 = make_float4(0.f,0.f,0.f,0.f);
    float4 xvAc = zero4, xvAn = zero4, xvBc = zero4, xvBn = zero4;
    if (t < HD_) {
        if (0 < lenA) xvAc = xcA[(size_t)pA(0) << 8];
        if (1 < lenA) xvAn = xcA[(size_t)pA(1) << 8];
        if (0 < lenB) xvBc = xcB[(size_t)pB(0) << 8];
        if (1 < lenB) xvBn = xcB[(size_t)pB(1) << 8];
    }
    __syncthreads();

    int maxlen = lenA > lenB ? lenA : lenB;
    for (int it = 0; it <= maxlen; it++) {
        // ---------------- even interval: RD B(it-1), MV A(it) ----------------
        if (it >= 1 && it - 1 < lenB) {
            if (t < HD_) {
                float4 xu = xvBc; xvBc = xvBn;
                if (it + 1 < lenB) xvBn = xcB[(size_t)pB(it + 1) << 8];  // load before store
                float hn = reduce_step(psB, xu, cB, h_B, j);
                outB[(size_t)pB(it - 1) * 256 + oco] = hn;
            }
        }
        if (it < lenA) matvec_step(w, h_A, psA, j, q);
        BAR_LDS();
        // ---------------- odd interval: RD A(it), MV B(it) ----------------
        if (it < lenA) {
            if (t < HD_) {
                float4 xu = xvAc; xvAc = xvAn;
                if (it + 2 < lenA) xvAn = xcA[(size_t)pA(it + 2) << 8];
                float hn = reduce_step(psA, xu, cA, h_A, j);
                outA[(size_t)pA(it) * 256 + oco] = hn;
            }
        }
        if (it < lenB) matvec_step(w, h_B, psB, j, q);
        BAR_LDS();
    }

    if (t < HD_) {
        if (hTA != nullptr) { hTA[t] = h_A[t]; cTA[t] = cA; }
        if (hTB != nullptr) { hTB[t] = h_B[t]; cTB[t] = cB; }
    }
}

__global__ void __launch_bounds__(512, 1)
lstm1_kernel(const int* __restrict__ lengths, const int* __restrict__ seg_off,
             const float* __restrict__ Whh_f, const float* __restrict__ Whh_b,
             const float* __restrict__ xproj, float* __restrict__ lstm_packed,
             float* __restrict__ hinit, float* __restrict__ cinit)
{
    int cid = blockIdx.x;                 // 256 = 32b * 4segpair * 2dir
    int b = cid >> 3, sp = (cid >> 1) & 3, dir = cid & 1;
    int segA = 2*sp, segB = 2*sp + 1;
    int lenA = lengths[b*NSEG_ + segA], lenB = lengths[b*NSEG_ + segB];
    int pbA  = seg_off[b*NSEG_ + segA], pbB  = seg_off[b*NSEG_ + segB];
    const float* Whh = dir ? Whh_b : Whh_f;
    float* hT = nullptr; float* cT = nullptr;
    if (sp == 3) {                        // segB == 7: final states feed LSTM2 init
        hT = hinit + (dir*B_ + b)*HD_;
        cT = cinit + (dir*B_ + b)*HD_;
    }
    const float* xp = xproj + ((size_t)b << 20);
    float* outp = lstm_packed + (size_t)b*T_*256;
    lstm_fused(Whh, xp, xp, outp, outp, pbA, lenA, pbB, lenB, dir,
               nullptr, nullptr, nullptr, nullptr,
               nullptr, nullptr, hT, cT);
}

__global__ void __launch_bounds__(512, 1)
lstm2_kernel(const int* __restrict__ new_len, const int* __restrict__ pairs,
             const float* __restrict__ Whh_f, const float* __restrict__ Whh_b,
             const float* __restrict__ xproj, float* __restrict__ lstm_packed,
             const float* __restrict__ hinit, const float* __restrict__ cinit)
{
    int cid = blockIdx.x;                 // 32 = 16 pairs * 2 dir
    int dir = cid >> 4, pi = cid & 15;
    int bA = pairs[2*pi], bB = pairs[2*pi + 1];
    int lenA = new_len[bA], lenB = new_len[bB];
    const float* Whh = dir ? Whh_b : Whh_f;
    lstm_fused(Whh,
               xproj + ((size_t)bA << 20), xproj + ((size_t)bB << 20),
               lstm_packed + (size_t)bA*T_*256, lstm_packed + (size_t)bB*T_*256,
               0, lenA, 0, lenB, dir,
               hinit + (dir*B_ + bA)*HD_, cinit + (dir*B_ + bA)*HD_,
               hinit + (dir*B_ + bB)*HD_, cinit + (dir*B_ + bB)*HD_,
               nullptr, nullptr, nullptr, nullptr);
}

// ---------------- emission: em[b][p][s] = lstm2[b][p][:] . Wlin[s][:] + blin[s] ----------------
__global__ void __launch_bounds__(256)
emission_kernel(const float* __restrict__ lstm_packed, const float* __restrict__ Wlin,
                const float* __restrict__ blin, float* __restrict__ emis,
                const int* __restrict__ new_len)
{
    int b  = blockIdx.y;
    int nl = new_len[b];
    int p0 = blockIdx.x * 16;
    if (p0 >= nl) return;
    int pl = threadIdx.x >> 4, s = threadIdx.x & 15;
    int p  = p0 + pl;
    const float4* xr = (const float4*)(lstm_packed + ((size_t)b*T_ + p) * 256);
    const float4* wr = (const float4*)(Wlin + (size_t)s * 256);
    float ax = 0.f, ay = 0.f, az = 0.f, aw = 0.f;
    #pragma unroll
    for (int i = 0; i < 64; i++) {
        float4 a = xr[i]; float4 ww = wr[i];
        ax = fmaf(a.x, ww.x, ax); ay = fmaf(a.y, ww.y, ay);
        az = fmaf(a.z, ww.z, az); aw = fmaf(a.w, ww.w, aw);
    }
    if (p < nl) emis[((size_t)b*T_ + p)*K_ + s] = (ax + ay) + (az + aw) + blin[s];
}

// ---------------- Viterbi: one block (1 wave) per batch element ----------------
__global__ void __launch_bounds__(64)
viterbi_kernel(const float* __restrict__ emis, const float* __restrict__ start,
               const float* __restrict__ trans, const float* __restrict__ endv,
               const int* __restrict__ new_len, float* __restrict__ out)
{
    int b    = blockIdx.x;
    int nl   = new_len[b];
    int lane = threadIdx.x;          // 64 lanes: 4 q-groups x 16 states
    int s    = lane & 15, q4 = lane >> 4;

    __shared__ unsigned char hist[T_ * K_];   // 16 KB
    __shared__ unsigned char tagb[T_];

    float tr[4];
    #pragma unroll
    for (int jj = 0; jj < 4; jj++) tr[jj] = trans[(q4*4 + jj)*K_ + s];

    const float* em = emis + (size_t)b * T_ * K_;
    float sc = start[s] + em[s];     // p = 0 (always valid)

    for (int p = 1; p < nl; p++) {
        float e = em[p*K_ + s];
        float m = -3.4e38f; int a = 0;
        #pragma unroll
        for (int jj = 0; jj < 4; jj++) {
            int q   = q4*4 + jj;
            float sq = __shfl(sc, q, 16);
            float v  = sq + tr[jj];
            if (v > m) { m = v; a = q; }
        }
        #pragma unroll
        for (int d = 16; d < 64; d <<= 1) {
            float mo = __shfl_xor(m, d);
            int   ao = __shfl_xor(a, d);
            if (mo > m || (mo == m && ao < a)) { m = mo; a = ao; }
        }
        sc = m + e;
        if (lane < K_) hist[p*K_ + s] = (unsigned char)a;
    }

    float m = sc + endv[s]; int a = s;
    #pragma unroll
    for (int d = 1; d < 16; d <<= 1) {
        float mo = __shfl_xor(m, d);
        int   ao = __shfl_xor(a, d);
        if (mo > m || (mo == m && ao < a)) { m = mo; a = ao; }
    }
    int last = a;
    if (lane == 0) out[T_*B_ + b] = m;
    __syncthreads();

    for (int i = lane; i < T_; i += 64) tagb[i] = (unsigned char)last;
    __syncthreads();
    if (lane == 0) {
        int cur = last;
        for (int j = nl - 2; j >= 0; j--) {
            cur = hist[(j+1)*K_ + cur];
            tagb[j] = (unsigned char)cur;
        }
    }
    __syncthreads();
    for (int i = lane; i < T_; i += 64) out[(size_t)i*B_ + b] = (float)tagb[i];
}

// ---------------- host ----------------
extern "C" void kernel_launch(void* const* d_in, const int* in_sizes, int n_in,
                              void* d_out, int out_size, void* d_ws, size_t ws_size,
                              hipStream_t stream)
{
    (void)in_sizes; (void)n_in; (void)out_size; (void)ws_size;
    const int*   texts   = (const int*)  d_in[0];
    const int*   lengths = (const int*)  d_in[1];
    const float* emb     = (const float*)d_in[2];
    const float* Wih_f   = (const float*)d_in[3];
    const float* Whh_f   = (const float*)d_in[4];
    const float* bih_f   = (const float*)d_in[5];
    const float* bhh_f   = (const float*)d_in[6];
    const float* Wih_b   = (const float*)d_in[7];
    const float* Whh_b   = (const float*)d_in[8];
    const float* bih_b   = (const float*)d_in[9];
    const float* bhh_b   = (const float*)d_in[10];
    const float* Wlin    = (const float*)d_in[11];
    const float* blin    = (const float*)d_in[12];
    const float* c_start = (const float*)d_in[13];
    const float* c_trans = (const float*)d_in[14];
    const float* c_end   = (const float*)d_in[15];
    float* out = (float*)d_out;

    // workspace carve (~163 MB total, all 16B-aligned)
    char* w = (char*)d_ws;
    int*   seg_off     = (int*)(w);                      // 256 ints
    int*   new_len     = (int*)(w + 1024);               // 32 ints
    int*   pairs       = (int*)(w + 2048);               // 32 ints
    float* bias1       = (float*)(w + 4096);             // 1024 f
    float* WT1         = (float*)(w + 8192);             // 262144 f (1 MB)
    float* hinit       = (float*)(w + 8192 + 1048576);   // 8192 f
    float* cinit       = hinit + 8192;                   // 8192 f
    float* lstm_packed = cinit + 8192;                   // 32*1024*256 f (32 MB)
    float* xproj       = lstm_packed + (size_t)B_*T_*256;    // 32*1024*1024 f (128 MB)
    float* emis        = xproj + ((size_t)B_ << 20);         // 32*1024*16 f (2 MB)

    prep_kernel<<<128, 256, 0, stream>>>(lengths, seg_off, new_len, pairs,
                                         bih_f, bhh_f, bih_b, bhh_b, bias1,
                                         Wih_f, Wih_b, WT1);
    proj_kernel<0><<<dim3(32, 4, B_), 256, 0, stream>>>(texts, emb, WT1, bias1,
                                                        lstm_packed, xproj, seg_off, new_len);
    lstm1_kernel<<<256, 512, 0, stream>>>(lengths, seg_off, Whh_f, Whh_b,
                                          xproj, lstm_packed, hinit, cinit);
    proj_kernel<1><<<dim3(32, 4, B_), 256, 0, stream>>>(texts, emb, WT1, bias1,
                                                        lstm_packed, xproj, seg_off, new_len);
    lstm2_kernel<<<32, 512, 0, stream>>>(new_len, pairs, Whh_f, Whh_b,
                                         xproj, lstm_packed, hinit, cinit);
    emission_kernel<<<dim3(64, B_), 256, 0, stream>>>(lstm_packed, Wlin, blin, emis, new_len);
    viterbi_kernel<<<B_, 64, 0, stream>>>(emis, c_start, c_trans, c_end, new_len, out);
}